// Round 5
// baseline (40.507 us; speedup 1.0000x reference)
//
#include <hip/hip_runtime.h>
#include <math.h>

#define BATCH   512
#define IN_DIM  256
#define OUT_DIM 256
#define NDEG    6     // degree+1

// R5 geometry: 256 threads = 8 o-lanes (minor) x 32 i-segments, 16 b-accs
// per thread (coef reuse 16x), i-range split in half across blockIdx.z
// -> 2048 blocks = 8 blocks/CU = 32 waves/CU for latency hiding.
#define OT     8     // o per block
#define NSEG   32    // i-segments per block
#define ISEG   4     // i's per segment (NSEG*ISEG == IN_DIM/NZ)
#define NB     16    // b per block (register accumulators)
#define NZ     2     // i-split factor (blockIdx.z)
#define IHALF  (IN_DIM / NZ)   // 128

// ---------------------------------------------------------------------------
// LSE_d(x*d + w_d) = log( sum_d e^{w_d} * t^d ),  t = e^x.
// out[b,o] = ln2 * sum_i [ log2 P_io(t) - log2 Q_io(t) ]
// (P,Q) evaluated as packed dual-f32 Horner (v_pk_fma_f32), coefficients
// pre-interleaved (p_d,q_d); log2 batched over pairs of i (product <= ~2e22,
// f32-safe). R5: occupancy 2x via i-split + batched seg loads + b64 t-reads.
// ---------------------------------------------------------------------------

typedef float v2f __attribute__((ext_vector_type(2)));

__device__ __forceinline__ v2f pk_fma(v2f a, v2f b, v2f c) {
    v2f d;
    asm("v_pk_fma_f32 %0, %1, %2, %3" : "=v"(d) : "v"(a), "v"(b), "v"(c));
    return d;
}
__device__ __forceinline__ v2f pk_mul(v2f a, v2f b) {
    v2f d;
    asm("v_pk_mul_f32 %0, %1, %2" : "=v"(d) : "v"(a), "v"(b));
    return d;
}

// pkT[(i*3+w)*256 + o] = float4 of interleaved pairs:
//   w=0: (p0,q0,p1,q1)  w=1: (p2,q2,p3,q3)  w=2: (p4,q4,p5,q5)
__global__ void prep_pack(const float* __restrict__ wp,
                          const float* __restrict__ wq,
                          float4* __restrict__ pkT) {
    int j = blockIdx.x * blockDim.x + threadIdx.x;   // j = i*OUT_DIM + o
    if (j >= IN_DIM * OUT_DIM) return;
    const int i = j >> 8, o = j & 255;
    const float2* wp2 = (const float2*)wp;
    const float2* wq2 = (const float2*)wq;
    float2 p0 = wp2[j * 3], p1 = wp2[j * 3 + 1], p2 = wp2[j * 3 + 2];
    float2 q0 = wq2[j * 3], q1 = wq2[j * 3 + 1], q2 = wq2[j * 3 + 2];
    pkT[(i * 3 + 0) * OUT_DIM + o] =
        make_float4(__expf(p0.x), __expf(q0.x), __expf(p0.y), __expf(q0.y));
    pkT[(i * 3 + 1) * OUT_DIM + o] =
        make_float4(__expf(p1.x), __expf(q1.x), __expf(p1.y), __expf(q1.y));
    pkT[(i * 3 + 2) * OUT_DIM + o] =
        make_float4(__expf(p2.x), __expf(q2.x), __expf(p2.y), __expf(q2.y));
}

// Grid = (OUT_DIM/OT=32, BATCH/NB=32, NZ=2) = 2048 blocks = 8/CU.
__launch_bounds__(256, 8)
__global__ void tropical_main(const float* __restrict__ x,
                              const float4* __restrict__ pkT,
                              float* __restrict__ partial) {
    // Phase A: t[b][i_local], 16 b x 128 i (2048 f). Phase B: reduce buffer,
    // NSEG slabs of stride NB*OT+1 = 129 (4128 f). Shared allocation.
    __shared__ float lds[NSEG * (NB * OT + 1)];   // 4128 floats = 16.5 KiB

    const int tid = threadIdx.x;
    const int o_l = tid & (OT - 1);
    const int seg = tid >> 3;
    const int o   = blockIdx.x * OT + o_l;
    const int b0  = blockIdx.y * NB;
    const int iz  = blockIdx.z * IHALF;           // global i offset

    // ---- stage t = exp(x): 16 b-rows x this block's 128-i window ----
    {
        const int br  = tid >> 4;                 // 0..15
        const int c16 = tid & 15;                 // 0..15, 8 floats each
        const float* xr = x + (size_t)(b0 + br) * IN_DIM + iz + c16 * 8;
        const float4 v0 = *(const float4*)(xr);
        const float4 v1 = *(const float4*)(xr + 4);
        const int base = br * IHALF + c16 * 8;
        lds[base + 0] = __expf(v0.x);
        lds[base + 1] = __expf(v0.y);
        lds[base + 2] = __expf(v0.z);
        lds[base + 3] = __expf(v0.w);
        lds[base + 4] = __expf(v1.x);
        lds[base + 5] = __expf(v1.y);
        lds[base + 6] = __expf(v1.z);
        lds[base + 7] = __expf(v1.w);
    }
    __syncthreads();

    float acc[NB];
#pragma unroll
    for (int b = 0; b < NB; ++b) acc[b] = 0.f;

    const int i_loc = seg * ISEG;                 // local i base (0..124)
    const float4* __restrict__ cbase =
        pkT + (size_t)((iz + i_loc) * 3) * OUT_DIM + o;
    const float* __restrict__ tbase = lds + i_loc;

#pragma unroll
    for (int g = 0; g < ISEG / 2; ++g) {          // 2 i-pairs, fully unrolled
        const int iA = 2 * g, iB = 2 * g + 1;
        const float4 a0 = cbase[(iA * 3 + 0) * OUT_DIM];
        const float4 a1 = cbase[(iA * 3 + 1) * OUT_DIM];
        const float4 a2 = cbase[(iA * 3 + 2) * OUT_DIM];
        const float4 e0 = cbase[(iB * 3 + 0) * OUT_DIM];
        const float4 e1 = cbase[(iB * 3 + 1) * OUT_DIM];
        const float4 e2 = cbase[(iB * 3 + 2) * OUT_DIM];
        const v2f CA0 = {a0.x, a0.y}, CA1 = {a0.z, a0.w};
        const v2f CA2 = {a1.x, a1.y}, CA3 = {a1.z, a1.w};
        const v2f CA4 = {a2.x, a2.y}, CA5 = {a2.z, a2.w};
        const v2f CB0 = {e0.x, e0.y}, CB1 = {e0.z, e0.w};
        const v2f CB2 = {e1.x, e1.y}, CB3 = {e1.z, e1.w};
        const v2f CB4 = {e2.x, e2.y}, CB5 = {e2.z, e2.w};

#pragma unroll
        for (int b = 0; b < NB; ++b) {
            const float2 tt = *(const float2*)(tbase + b * IHALF + iA); // b64
            const v2f T0 = {tt.x, tt.x};
            const v2f T1 = {tt.y, tt.y};
            v2f PQ0 = pk_fma(CA5, T0, CA4);       // packed Horner (P,Q)
            PQ0 = pk_fma(PQ0, T0, CA3);
            PQ0 = pk_fma(PQ0, T0, CA2);
            PQ0 = pk_fma(PQ0, T0, CA1);
            PQ0 = pk_fma(PQ0, T0, CA0);
            v2f PQ1 = pk_fma(CB5, T1, CB4);
            PQ1 = pk_fma(PQ1, T1, CB3);
            PQ1 = pk_fma(PQ1, T1, CB2);
            PQ1 = pk_fma(PQ1, T1, CB1);
            PQ1 = pk_fma(PQ1, T1, CB0);
            const v2f pr = pk_mul(PQ0, PQ1);      // (P_A*P_B, Q_A*Q_B)
            acc[b] += __log2f(pr.x) - __log2f(pr.y);
        }
    }

    __syncthreads();   // done with t; reuse LDS as reduce buffer
#pragma unroll
    for (int b = 0; b < NB; ++b)
        lds[seg * (NB * OT + 1) + b * OT + o_l] = acc[b];
    __syncthreads();

    if (tid < NB * OT) {
        const int br = tid >> 3, orr = tid & (OT - 1);
        float s = 0.f;
#pragma unroll
        for (int g2 = 0; g2 < NSEG; ++g2)
            s += lds[g2 * (NB * OT + 1) + br * OT + orr];
        partial[((size_t)blockIdx.z * BATCH + b0 + br) * OUT_DIM +
                blockIdx.x * OT + orr] = s;
    }
}

__global__ void tropical_reduce(const float4* __restrict__ partial,
                                float4* __restrict__ out) {
    const int j = blockIdx.x * blockDim.x + threadIdx.x;  // float4 index
    const int N4 = BATCH * OUT_DIM / 4;
    const float4 a = partial[j];
    const float4 b = partial[j + N4];
    const float k = 0.6931471805599453f;   // ln2
    out[j] = make_float4((a.x + b.x) * k, (a.y + b.y) * k,
                         (a.z + b.z) * k, (a.w + b.w) * k);
}

// Fallback (workspace too small): direct stabilized LSE.
__global__ void tropical_fallback(const float* __restrict__ x,
                                  const float* __restrict__ wp,
                                  const float* __restrict__ wq,
                                  float* __restrict__ out) {
    const int o = blockIdx.x * 16 + (threadIdx.x & 15);
    const int b = blockIdx.y * 16 + (threadIdx.x >> 4);
    float acc = 0.f;
    for (int i = 0; i < IN_DIM; ++i) {
        const float xv = x[b * IN_DIM + i];
        const float* p = wp + (size_t)(i * OUT_DIM + o) * NDEG;
        const float* q = wq + (size_t)(i * OUT_DIM + o) * NDEG;
        float lp[NDEG], lq[NDEG], mP = -1e30f, mQ = -1e30f;
#pragma unroll
        for (int d = 0; d < NDEG; ++d) {
            lp[d] = xv * d + p[d]; mP = fmaxf(mP, lp[d]);
            lq[d] = xv * d + q[d]; mQ = fmaxf(mQ, lq[d]);
        }
        float sP = 0.f, sQ = 0.f;
#pragma unroll
        for (int d = 0; d < NDEG; ++d) {
            sP += __expf(lp[d] - mP);
            sQ += __expf(lq[d] - mQ);
        }
        acc += (mP + __logf(sP)) - (mQ + __logf(sQ));
    }
    out[b * OUT_DIM + o] = acc;
}

extern "C" void kernel_launch(void* const* d_in, const int* in_sizes, int n_in,
                              void* d_out, int out_size, void* d_ws, size_t ws_size,
                              hipStream_t stream) {
    const float* x  = (const float*)d_in[0];
    // d_in[1] = slopes (arange(6)) — implicit in the polynomial powers.
    const float* wp = (const float*)d_in[2];
    const float* wq = (const float*)d_in[3];
    float* out = (float*)d_out;

    const size_t pk_bytes = (size_t)IN_DIM * OUT_DIM * 12 * sizeof(float);       // 3 MiB
    const size_t pa_bytes = (size_t)NZ * BATCH * OUT_DIM * sizeof(float);        // 1 MiB

    if (ws_size >= pk_bytes + pa_bytes) {
        float4* pkT = (float4*)d_ws;
        float*  pa  = (float*)((char*)d_ws + pk_bytes);

        prep_pack<<<(IN_DIM * OUT_DIM + 255) / 256, 256, 0, stream>>>(wp, wq, pkT);

        dim3 grid(OUT_DIM / OT, BATCH / NB, NZ);   // 32 x 32 x 2 = 2048 blocks
        tropical_main<<<grid, 256, 0, stream>>>(x, (const float4*)pkT, pa);

        tropical_reduce<<<(BATCH * OUT_DIM / 4) / 256, 256, 0, stream>>>(
            (const float4*)pa, (float4*)out);
    } else {
        dim3 grid(OUT_DIM / 16, BATCH / 16);
        tropical_fallback<<<grid, 256, 0, stream>>>(x, wp, wq, out);
    }
}

// Round 6
// 25.289 us; speedup vs baseline: 1.6018x; 1.6018x over previous
//
#include <hip/hip_runtime.h>
#include <math.h>

#define BATCH   512
#define IN_DIM  256
#define OUT_DIM 256
#define NDEG    6     // degree+1

// R6 geometry: 256 threads = 8 o-lanes (minor) x 32 i-segments; NB=8
// b-accumulators per thread (coef reuse 8x) so the live register set
// (acc8 + double-buffered coefs) fits the 64-VGPR occupancy tier.
// Grid = (32 o-blocks, 64 b-blocks) = 2048 blocks = 8/CU = 32 waves/CU.
#define OT     8     // o per block
#define NSEG   32    // i-segments per block
#define ISEG   8     // i's per segment (NSEG*ISEG == IN_DIM)
#define NB     8     // b per block (register accumulators)

// ---------------------------------------------------------------------------
// LSE_d(x*d + w_d) = log( sum_d e^{w_d} * t^d ),  t = e^x.
// out[b,o] = ln2 * sum_i [ log2 P_io(t) - log2 Q_io(t) ]
// (P,Q) as packed dual-f32 Horner (v_pk_fma_f32), coefficients pre-
// interleaved (p_d,q_d); log2 batched over i-pairs (product <= ~2e22, safe).
// R6: NB=8 for register headroom + explicit coef double-buffer prefetch.
// ---------------------------------------------------------------------------

typedef float v2f __attribute__((ext_vector_type(2)));

__device__ __forceinline__ v2f pk_fma(v2f a, v2f b, v2f c) {
    v2f d;
    asm("v_pk_fma_f32 %0, %1, %2, %3" : "=v"(d) : "v"(a), "v"(b), "v"(c));
    return d;
}
__device__ __forceinline__ v2f pk_mul(v2f a, v2f b) {
    v2f d;
    asm("v_pk_mul_f32 %0, %1, %2" : "=v"(d) : "v"(a), "v"(b));
    return d;
}

// pkT[(i*3+w)*256 + o] = float4 of interleaved pairs:
//   w=0: (p0,q0,p1,q1)  w=1: (p2,q2,p3,q3)  w=2: (p4,q4,p5,q5)
__global__ void prep_pack(const float* __restrict__ wp,
                          const float* __restrict__ wq,
                          float4* __restrict__ pkT) {
    int j = blockIdx.x * blockDim.x + threadIdx.x;   // j = i*OUT_DIM + o
    if (j >= IN_DIM * OUT_DIM) return;
    const int i = j >> 8, o = j & 255;
    const float2* wp2 = (const float2*)wp;
    const float2* wq2 = (const float2*)wq;
    float2 p0 = wp2[j * 3], p1 = wp2[j * 3 + 1], p2 = wp2[j * 3 + 2];
    float2 q0 = wq2[j * 3], q1 = wq2[j * 3 + 1], q2 = wq2[j * 3 + 2];
    pkT[(i * 3 + 0) * OUT_DIM + o] =
        make_float4(__expf(p0.x), __expf(q0.x), __expf(p0.y), __expf(q0.y));
    pkT[(i * 3 + 1) * OUT_DIM + o] =
        make_float4(__expf(p1.x), __expf(q1.x), __expf(p1.y), __expf(q1.y));
    pkT[(i * 3 + 2) * OUT_DIM + o] =
        make_float4(__expf(p2.x), __expf(q2.x), __expf(p2.y), __expf(q2.y));
}

// Computes the packed (P,Q) Horner + pair-batched log2 for i-pair (iA,iA+1)
// using 6 float4 coefficient registers already in hand.
#define COMPUTE(iA, a0, a1, a2, e0, e1, e2)                                   \
    {                                                                         \
        const v2f CA0 = {a0.x, a0.y}, CA1 = {a0.z, a0.w};                     \
        const v2f CA2 = {a1.x, a1.y}, CA3 = {a1.z, a1.w};                     \
        const v2f CA4 = {a2.x, a2.y}, CA5 = {a2.z, a2.w};                     \
        const v2f CB0 = {e0.x, e0.y}, CB1 = {e0.z, e0.w};                     \
        const v2f CB2 = {e1.x, e1.y}, CB3 = {e1.z, e1.w};                     \
        const v2f CB4 = {e2.x, e2.y}, CB5 = {e2.z, e2.w};                     \
        _Pragma("unroll")                                                     \
        for (int b = 0; b < NB; ++b) {                                        \
            const float2 tt = *(const float2*)(tb + b * IN_DIM + (iA));       \
            const v2f T0 = {tt.x, tt.x};                                      \
            const v2f T1 = {tt.y, tt.y};                                      \
            v2f PQ0 = pk_fma(CA5, T0, CA4);                                   \
            PQ0 = pk_fma(PQ0, T0, CA3);                                       \
            PQ0 = pk_fma(PQ0, T0, CA2);                                       \
            PQ0 = pk_fma(PQ0, T0, CA1);                                       \
            PQ0 = pk_fma(PQ0, T0, CA0);                                       \
            v2f PQ1 = pk_fma(CB5, T1, CB4);                                   \
            PQ1 = pk_fma(PQ1, T1, CB3);                                       \
            PQ1 = pk_fma(PQ1, T1, CB2);                                       \
            PQ1 = pk_fma(PQ1, T1, CB1);                                       \
            PQ1 = pk_fma(PQ1, T1, CB0);                                       \
            const v2f pr = pk_mul(PQ0, PQ1);                                  \
            acc[b] += __log2f(pr.x) - __log2f(pr.y);                          \
        }                                                                     \
    }

// Grid = (OUT_DIM/OT = 32, BATCH/NB = 64) = 2048 blocks = 8/CU.
__launch_bounds__(256, 4)
__global__ void tropical_main(const float* __restrict__ x,
                              const float4* __restrict__ pkT,
                              float* __restrict__ out) {
    // Phase A: t[b][i], 8 b x 256 i (2048 f). Phase B: reduce buffer,
    // NSEG slabs of stride NB*OT+1 = 65 (2080 f). Shared allocation.
    __shared__ float lds[NSEG * (NB * OT + 1)];   // 2080 floats = 8.3 KiB

    const int tid = threadIdx.x;
    const int o_l = tid & (OT - 1);
    const int seg = tid >> 3;
    const int o   = blockIdx.x * OT + o_l;
    const int b0  = blockIdx.y * NB;

    // ---- stage t = exp(x): 8 b-rows x 256 i (8 floats / thread) ----
    {
        const int r = tid >> 5;            // 0..7
        const int c = (tid & 31) * 8;      // 0..248
        const float* xr = x + (size_t)(b0 + r) * IN_DIM + c;
        const float4 v0 = *(const float4*)(xr);
        const float4 v1 = *(const float4*)(xr + 4);
        float4 w0, w1;
        w0.x = __expf(v0.x); w0.y = __expf(v0.y);
        w0.z = __expf(v0.z); w0.w = __expf(v0.w);
        w1.x = __expf(v1.x); w1.y = __expf(v1.y);
        w1.z = __expf(v1.z); w1.w = __expf(v1.w);
        *(float4*)&lds[r * IN_DIM + c]     = w0;
        *(float4*)&lds[r * IN_DIM + c + 4] = w1;
    }
    __syncthreads();

    float acc[NB];
#pragma unroll
    for (int b = 0; b < NB; ++b) acc[b] = 0.f;

    const int i0 = seg * ISEG;
    const float4* __restrict__ cbase = pkT + (size_t)(i0 * 3) * OUT_DIM + o;
    const float* __restrict__ tb = lds + i0;

    // ---- double-buffered i-pair groups (iA = 0,2,4,6) ----
    float4 A0 = cbase[0 * OUT_DIM], A1 = cbase[1 * OUT_DIM], A2 = cbase[2 * OUT_DIM];
    float4 E0 = cbase[3 * OUT_DIM], E1 = cbase[4 * OUT_DIM], E2 = cbase[5 * OUT_DIM];

    float4 B0 = cbase[6 * OUT_DIM], B1 = cbase[7 * OUT_DIM], B2 = cbase[8 * OUT_DIM];
    float4 F0 = cbase[9 * OUT_DIM], F1 = cbase[10 * OUT_DIM], F2 = cbase[11 * OUT_DIM];
    COMPUTE(0, A0, A1, A2, E0, E1, E2);

    A0 = cbase[12 * OUT_DIM]; A1 = cbase[13 * OUT_DIM]; A2 = cbase[14 * OUT_DIM];
    E0 = cbase[15 * OUT_DIM]; E1 = cbase[16 * OUT_DIM]; E2 = cbase[17 * OUT_DIM];
    COMPUTE(2, B0, B1, B2, F0, F1, F2);

    B0 = cbase[18 * OUT_DIM]; B1 = cbase[19 * OUT_DIM]; B2 = cbase[20 * OUT_DIM];
    F0 = cbase[21 * OUT_DIM]; F1 = cbase[22 * OUT_DIM]; F2 = cbase[23 * OUT_DIM];
    COMPUTE(4, A0, A1, A2, E0, E1, E2);

    COMPUTE(6, B0, B1, B2, F0, F1, F2);

    __syncthreads();   // done with t; reuse LDS as reduce buffer
#pragma unroll
    for (int b = 0; b < NB; ++b)
        lds[seg * (NB * OT + 1) + b * OT + o_l] = acc[b];
    __syncthreads();

    if (tid < NB * OT) {
        const int br = tid >> 3, orr = tid & (OT - 1);
        float s = 0.f;
#pragma unroll
        for (int g = 0; g < NSEG; ++g)
            s += lds[g * (NB * OT + 1) + br * OT + orr];
        out[(size_t)(b0 + br) * OUT_DIM + blockIdx.x * OT + orr] =
            s * 0.6931471805599453f;   // * ln2
    }
}

// Fallback (workspace too small): direct stabilized LSE.
__global__ void tropical_fallback(const float* __restrict__ x,
                                  const float* __restrict__ wp,
                                  const float* __restrict__ wq,
                                  float* __restrict__ out) {
    const int o = blockIdx.x * 16 + (threadIdx.x & 15);
    const int b = blockIdx.y * 16 + (threadIdx.x >> 4);
    float acc = 0.f;
    for (int i = 0; i < IN_DIM; ++i) {
        const float xv = x[b * IN_DIM + i];
        const float* p = wp + (size_t)(i * OUT_DIM + o) * NDEG;
        const float* q = wq + (size_t)(i * OUT_DIM + o) * NDEG;
        float lp[NDEG], lq[NDEG], mP = -1e30f, mQ = -1e30f;
#pragma unroll
        for (int d = 0; d < NDEG; ++d) {
            lp[d] = xv * d + p[d]; mP = fmaxf(mP, lp[d]);
            lq[d] = xv * d + q[d]; mQ = fmaxf(mQ, lq[d]);
        }
        float sP = 0.f, sQ = 0.f;
#pragma unroll
        for (int d = 0; d < NDEG; ++d) {
            sP += __expf(lp[d] - mP);
            sQ += __expf(lq[d] - mQ);
        }
        acc += (mP + __logf(sP)) - (mQ + __logf(sQ));
    }
    out[b * OUT_DIM + o] = acc;
}

extern "C" void kernel_launch(void* const* d_in, const int* in_sizes, int n_in,
                              void* d_out, int out_size, void* d_ws, size_t ws_size,
                              hipStream_t stream) {
    const float* x  = (const float*)d_in[0];
    // d_in[1] = slopes (arange(6)) — implicit in the polynomial powers.
    const float* wp = (const float*)d_in[2];
    const float* wq = (const float*)d_in[3];
    float* out = (float*)d_out;

    const size_t pk_bytes = (size_t)IN_DIM * OUT_DIM * 12 * sizeof(float);  // 3 MiB

    if (ws_size >= pk_bytes) {
        float4* pkT = (float4*)d_ws;
        prep_pack<<<(IN_DIM * OUT_DIM + 255) / 256, 256, 0, stream>>>(wp, wq, pkT);

        dim3 grid(OUT_DIM / OT, BATCH / NB);   // 32 x 64 = 2048 blocks
        tropical_main<<<grid, 256, 0, stream>>>(x, (const float4*)pkT, out);
    } else {
        dim3 grid(OUT_DIM / 16, BATCH / 16);
        tropical_fallback<<<grid, 256, 0, stream>>>(x, wp, wq, out);
    }
}

// Round 7
// 25.044 us; speedup vs baseline: 1.6175x; 1.0098x over previous
//
#include <hip/hip_runtime.h>
#include <math.h>

#define BATCH   512
#define IN_DIM  256
#define OUT_DIM 256
#define NDEG    6     // degree+1

// Geometry (R6-proven): 256 threads = 8 o-lanes x 32 i-segments; NB=8
// b-accumulators per thread; explicit coef double-buffer.
// R7: coefficient layout is LANE-ORDERED so each of the 24 per-thread
// coefficient loads is one contiguous 1KB wave transaction (16B x 64 lanes),
// instead of 8 scattered 128B lines (R6 pathology: ~192 line-requests/wave).
#define OT     8     // o per block
#define NSEG   32    // i-segments per block (tid>>3)
#define ISEG   8     // i's per segment
#define NB     8     // b per block (register accumulators)

// ---------------------------------------------------------------------------
// LSE_d(x*d + w_d) = log( sum_d e^{w_d} * t^d ),  t = e^x.
// out[b,o] = ln2 * sum_i [ log2 P_io(t) - log2 Q_io(t) ]
// (P,Q) as packed dual-f32 Horner (v_pk_fma_f32), coefficients pre-
// interleaved (p_d,q_d); log2 batched over i-pairs (product <= ~2e22, safe).
//
// pk2 layout: block index g5 = (o_blk*4 + seg_blk)*24 + k, lane = seg*8+o_l:
//   pk2[g5*64 + lane], k = ii*3 + w  (ii = i&7, w = word 0..2)
// so a wave (seg 0..7 x o_l 0..7) reads 64 consecutive float4 per step k.
// ---------------------------------------------------------------------------

typedef float v2f __attribute__((ext_vector_type(2)));

__device__ __forceinline__ v2f pk_fma(v2f a, v2f b, v2f c) {
    v2f d;
    asm("v_pk_fma_f32 %0, %1, %2, %3" : "=v"(d) : "v"(a), "v"(b), "v"(c));
    return d;
}
__device__ __forceinline__ v2f pk_mul(v2f a, v2f b) {
    v2f d;
    asm("v_pk_mul_f32 %0, %1, %2" : "=v"(d) : "v"(a), "v"(b));
    return d;
}

__global__ void prep_pack(const float* __restrict__ wp,
                          const float* __restrict__ wq,
                          float4* __restrict__ pk2) {
    int j = blockIdx.x * blockDim.x + threadIdx.x;   // j = i*OUT_DIM + o
    if (j >= IN_DIM * OUT_DIM) return;
    const int i = j >> 8, o = j & 255;
    const int seg_blk = i >> 6;          // 0..3  (wave within block)
    const int seg     = (i >> 3) & 7;    // 0..7  (seg within wave)
    const int ii      = i & 7;           // 0..7  (i within segment)
    const int o_blk   = o >> 3;          // 0..31
    const int o_l     = o & 7;           // 0..7
    const size_t base =
        ((size_t)(o_blk * 4 + seg_blk) * 24) * 64 + seg * 8 + o_l;

    const float2* wp2 = (const float2*)wp;
    const float2* wq2 = (const float2*)wq;
    float2 p0 = wp2[j * 3], p1 = wp2[j * 3 + 1], p2 = wp2[j * 3 + 2];
    float2 q0 = wq2[j * 3], q1 = wq2[j * 3 + 1], q2 = wq2[j * 3 + 2];
    pk2[base + (ii * 3 + 0) * 64] =
        make_float4(__expf(p0.x), __expf(q0.x), __expf(p0.y), __expf(q0.y));
    pk2[base + (ii * 3 + 1) * 64] =
        make_float4(__expf(p1.x), __expf(q1.x), __expf(p1.y), __expf(q1.y));
    pk2[base + (ii * 3 + 2) * 64] =
        make_float4(__expf(p2.x), __expf(q2.x), __expf(p2.y), __expf(q2.y));
}

// Packed (P,Q) Horner + pair-batched log2 for i-pair (iA,iA+1), 6 float4
// coefficient registers already in hand.
#define COMPUTE(iA, a0, a1, a2, e0, e1, e2)                                   \
    {                                                                         \
        const v2f CA0 = {a0.x, a0.y}, CA1 = {a0.z, a0.w};                     \
        const v2f CA2 = {a1.x, a1.y}, CA3 = {a1.z, a1.w};                     \
        const v2f CA4 = {a2.x, a2.y}, CA5 = {a2.z, a2.w};                     \
        const v2f CB0 = {e0.x, e0.y}, CB1 = {e0.z, e0.w};                     \
        const v2f CB2 = {e1.x, e1.y}, CB3 = {e1.z, e1.w};                     \
        const v2f CB4 = {e2.x, e2.y}, CB5 = {e2.z, e2.w};                     \
        _Pragma("unroll")                                                     \
        for (int b = 0; b < NB; ++b) {                                        \
            const float2 tt = *(const float2*)(tb + b * IN_DIM + (iA));       \
            const v2f T0 = {tt.x, tt.x};                                      \
            const v2f T1 = {tt.y, tt.y};                                      \
            v2f PQ0 = pk_fma(CA5, T0, CA4);                                   \
            PQ0 = pk_fma(PQ0, T0, CA3);                                       \
            PQ0 = pk_fma(PQ0, T0, CA2);                                       \
            PQ0 = pk_fma(PQ0, T0, CA1);                                       \
            PQ0 = pk_fma(PQ0, T0, CA0);                                       \
            v2f PQ1 = pk_fma(CB5, T1, CB4);                                   \
            PQ1 = pk_fma(PQ1, T1, CB3);                                       \
            PQ1 = pk_fma(PQ1, T1, CB2);                                       \
            PQ1 = pk_fma(PQ1, T1, CB1);                                       \
            PQ1 = pk_fma(PQ1, T1, CB0);                                       \
            const v2f pr = pk_mul(PQ0, PQ1);                                  \
            acc[b] += __log2f(pr.x) - __log2f(pr.y);                          \
        }                                                                     \
    }

// Grid = (OUT_DIM/OT = 32, BATCH/NB = 64) = 2048 blocks = 8/CU.
// NOTE: linear block id = x + 32y -> id%8 = o_blk%8, so all 64 b-blocks
// sharing a coefficient set land on one XCD: per-XCD coef set is 384KB, L2-hot.
__launch_bounds__(256, 4)
__global__ void tropical_main(const float* __restrict__ x,
                              const float4* __restrict__ pk2,
                              float* __restrict__ out) {
    // Phase A: t[b][i], 8 b x 256 i (2048 f). Phase B: reduce buffer,
    // NSEG slabs of stride NB*OT+1 = 65 (2080 f). Shared allocation.
    __shared__ float lds[NSEG * (NB * OT + 1)];   // 2080 floats = 8.3 KiB

    const int tid = threadIdx.x;
    const int o_l = tid & (OT - 1);
    const int b0  = blockIdx.y * NB;

    // ---- stage t = exp(x): 8 b-rows x 256 i (8 floats / thread) ----
    {
        const int r = tid >> 5;            // 0..7
        const int c = (tid & 31) * 8;      // 0..248
        const float* xr = x + (size_t)(b0 + r) * IN_DIM + c;
        const float4 v0 = *(const float4*)(xr);
        const float4 v1 = *(const float4*)(xr + 4);
        float4 w0, w1;
        w0.x = __expf(v0.x); w0.y = __expf(v0.y);
        w0.z = __expf(v0.z); w0.w = __expf(v0.w);
        w1.x = __expf(v1.x); w1.y = __expf(v1.y);
        w1.z = __expf(v1.z); w1.w = __expf(v1.w);
        *(float4*)&lds[r * IN_DIM + c]     = w0;
        *(float4*)&lds[r * IN_DIM + c + 4] = w1;
    }
    __syncthreads();

    float acc[NB];
#pragma unroll
    for (int b = 0; b < NB; ++b) acc[b] = 0.f;

    // Coalesced coefficient base: wave (tid>>6) x lane (tid&63).
    const int lane = tid & 63;
    const int wv   = tid >> 6;                         // seg_blk
    const float4* __restrict__ cb =
        pk2 + ((size_t)(blockIdx.x * 4 + wv) * 24) * 64 + lane;

    // t base: this thread's i-segment (same numbering as before).
    const int i0 = (tid >> 3) * ISEG;
    const float* __restrict__ tb = lds + i0;

    // ---- double-buffered i-pair groups (iA = 0,2,4,6); step stride 64 ----
    float4 A0 = cb[0 * 64],  A1 = cb[1 * 64],  A2 = cb[2 * 64];
    float4 E0 = cb[3 * 64],  E1 = cb[4 * 64],  E2 = cb[5 * 64];

    float4 B0 = cb[6 * 64],  B1 = cb[7 * 64],  B2 = cb[8 * 64];
    float4 F0 = cb[9 * 64],  F1 = cb[10 * 64], F2 = cb[11 * 64];
    COMPUTE(0, A0, A1, A2, E0, E1, E2);

    A0 = cb[12 * 64]; A1 = cb[13 * 64]; A2 = cb[14 * 64];
    E0 = cb[15 * 64]; E1 = cb[16 * 64]; E2 = cb[17 * 64];
    COMPUTE(2, B0, B1, B2, F0, F1, F2);

    B0 = cb[18 * 64]; B1 = cb[19 * 64]; B2 = cb[20 * 64];
    F0 = cb[21 * 64]; F1 = cb[22 * 64]; F2 = cb[23 * 64];
    COMPUTE(4, A0, A1, A2, E0, E1, E2);

    COMPUTE(6, B0, B1, B2, F0, F1, F2);

    __syncthreads();   // done with t; reuse LDS as reduce buffer
    const int seg = tid >> 3;
#pragma unroll
    for (int b = 0; b < NB; ++b)
        lds[seg * (NB * OT + 1) + b * OT + o_l] = acc[b];
    __syncthreads();

    if (tid < NB * OT) {
        const int br = tid >> 3, orr = tid & (OT - 1);
        float s = 0.f;
#pragma unroll
        for (int g = 0; g < NSEG; ++g)
            s += lds[g * (NB * OT + 1) + br * OT + orr];
        out[(size_t)(b0 + br) * OUT_DIM + blockIdx.x * OT + orr] =
            s * 0.6931471805599453f;   // * ln2
    }
}

// Fallback (workspace too small): direct stabilized LSE.
__global__ void tropical_fallback(const float* __restrict__ x,
                                  const float* __restrict__ wp,
                                  const float* __restrict__ wq,
                                  float* __restrict__ out) {
    const int o = blockIdx.x * 16 + (threadIdx.x & 15);
    const int b = blockIdx.y * 16 + (threadIdx.x >> 4);
    float acc = 0.f;
    for (int i = 0; i < IN_DIM; ++i) {
        const float xv = x[b * IN_DIM + i];
        const float* p = wp + (size_t)(i * OUT_DIM + o) * NDEG;
        const float* q = wq + (size_t)(i * OUT_DIM + o) * NDEG;
        float lp[NDEG], lq[NDEG], mP = -1e30f, mQ = -1e30f;
#pragma unroll
        for (int d = 0; d < NDEG; ++d) {
            lp[d] = xv * d + p[d]; mP = fmaxf(mP, lp[d]);
            lq[d] = xv * d + q[d]; mQ = fmaxf(mQ, lq[d]);
        }
        float sP = 0.f, sQ = 0.f;
#pragma unroll
        for (int d = 0; d < NDEG; ++d) {
            sP += __expf(lp[d] - mP);
            sQ += __expf(lq[d] - mQ);
        }
        acc += (mP + __logf(sP)) - (mQ + __logf(sQ));
    }
    out[b * OUT_DIM + o] = acc;
}

extern "C" void kernel_launch(void* const* d_in, const int* in_sizes, int n_in,
                              void* d_out, int out_size, void* d_ws, size_t ws_size,
                              hipStream_t stream) {
    const float* x  = (const float*)d_in[0];
    // d_in[1] = slopes (arange(6)) — implicit in the polynomial powers.
    const float* wp = (const float*)d_in[2];
    const float* wq = (const float*)d_in[3];
    float* out = (float*)d_out;

    const size_t pk_bytes = (size_t)IN_DIM * OUT_DIM * 12 * sizeof(float);  // 3 MiB

    if (ws_size >= pk_bytes) {
        float4* pk2 = (float4*)d_ws;
        prep_pack<<<(IN_DIM * OUT_DIM + 255) / 256, 256, 0, stream>>>(wp, wq, pk2);

        dim3 grid(OUT_DIM / OT, BATCH / NB);   // 32 x 64 = 2048 blocks
        tropical_main<<<grid, 256, 0, stream>>>(x, (const float4*)pk2, out);
    } else {
        dim3 grid(OUT_DIM / 16, BATCH / 16);
        tropical_fallback<<<grid, 256, 0, stream>>>(x, wp, wq, out);
    }
}